// Round 1
// baseline (576.442 us; speedup 1.0000x reference)
//
#include <hip/hip_runtime.h>

typedef __attribute__((ext_vector_type(8))) __bf16 bf16x8;
typedef __attribute__((ext_vector_type(4))) float f32x4;

#define NH 32
#define DH 80
#define SEQ 1024
#define NB 4
#define NT 4096
#define HID 2560
#define NQKV 7680
#define SM_SCALE 0.11180339887498948f

static __device__ __forceinline__ unsigned short f2bf(float f) {
  unsigned u = __builtin_bit_cast(unsigned, f);
  u += 0x7fffu + ((u >> 16) & 1u);
  return (unsigned short)(u >> 16);
}
static __device__ __forceinline__ float bf2f(unsigned short s) {
  unsigned u = (unsigned)s << 16;
  return __builtin_bit_cast(float, u);
}

// ---------------- fp32 -> bf16 convert (vectorized) ----------------
__global__ __launch_bounds__(256) void cvt_kernel(const float* __restrict__ in,
                                                  unsigned short* __restrict__ out,
                                                  int n4) {
  const float4* __restrict__ in4 = (const float4*)in;
  ushort4* __restrict__ out4 = (ushort4*)out;
  for (int i = blockIdx.x * blockDim.x + threadIdx.x; i < n4;
       i += gridDim.x * blockDim.x) {
    float4 v = in4[i];
    ushort4 o;
    o.x = f2bf(v.x);
    o.y = f2bf(v.y);
    o.z = f2bf(v.z);
    o.w = f2bf(v.w);
    out4[i] = o;
  }
}

// ---------------- bf16 MFMA GEMM: C[M][N] = A[M][K] @ B[N][K]^T + bias ------
// EPI 0: scatter q/k/v (bf16) into [B][H][S][D] buffers.
// EPI 1: plain fp32 C output.
template <int EPI>
__global__ __launch_bounds__(256) void gemm_kernel(
    const unsigned short* __restrict__ A, const unsigned short* __restrict__ Bm,
    const float* __restrict__ bias, unsigned short* __restrict__ Cq,
    unsigned short* __restrict__ Ck, unsigned short* __restrict__ Cv,
    float* __restrict__ Cf, int M, int N, int K) {
  // 128x128 tile, BK=32. Row stride 40 ushorts (80B) -> 2-way bank aliasing (free).
  __shared__ __align__(16) unsigned short As[128][40];
  __shared__ __align__(16) unsigned short Bs[128][40];
  const int tid = threadIdx.x;
  const int lane = tid & 63, w = tid >> 6;
  const int wr = w >> 1, wc = w & 1;
  const int lr = lane & 15, lg = lane >> 4;
  const int koff = lg * 8;
  const int m0 = blockIdx.y * 128, n0 = blockIdx.x * 128;
  const int srow = tid >> 2, scol = (tid & 3) * 8;

  f32x4 acc[4][4];
#pragma unroll
  for (int i = 0; i < 4; ++i)
#pragma unroll
    for (int j = 0; j < 4; ++j) acc[i][j] = (f32x4)0.0f;

  for (int k0 = 0; k0 < K; k0 += 32) {
    __syncthreads();
    *(bf16x8*)&As[srow][scol] = *(const bf16x8*)(A + (m0 + srow) * K + k0 + scol);
    *(bf16x8*)&As[srow + 64][scol] =
        *(const bf16x8*)(A + (m0 + srow + 64) * K + k0 + scol);
    *(bf16x8*)&Bs[srow][scol] = *(const bf16x8*)(Bm + (n0 + srow) * K + k0 + scol);
    *(bf16x8*)&Bs[srow + 64][scol] =
        *(const bf16x8*)(Bm + (n0 + srow + 64) * K + k0 + scol);
    __syncthreads();
    bf16x8 af[4], bfr[4];
#pragma unroll
    for (int i = 0; i < 4; ++i)
      af[i] = *(const bf16x8*)&As[wr * 64 + i * 16 + lr][koff];
#pragma unroll
    for (int j = 0; j < 4; ++j)
      bfr[j] = *(const bf16x8*)&Bs[wc * 64 + j * 16 + lr][koff];
#pragma unroll
    for (int i = 0; i < 4; ++i)
#pragma unroll
      for (int j = 0; j < 4; ++j)
        acc[i][j] =
            __builtin_amdgcn_mfma_f32_16x16x32_bf16(af[i], bfr[j], acc[i][j], 0, 0, 0);
  }

  if (EPI == 0) {
#pragma unroll
    for (int j = 0; j < 4; ++j) {
      const int col = n0 + wc * 64 + j * 16 + lr;
      const int sec = col / HID;           // 0=q 1=k 2=v (uniform within 16-col frag)
      const int rem = col - sec * HID;
      const int hh = rem / DH;
      const int dd = rem - hh * DH;
      unsigned short* dst = sec == 0 ? Cq : (sec == 1 ? Ck : Cv);
      const float bv = bias[col];
#pragma unroll
      for (int i = 0; i < 4; ++i) {
#pragma unroll
        for (int r = 0; r < 4; ++r) {
          const int t = m0 + wr * 64 + i * 16 + lg * 4 + r;
          const int bb = t >> 10, ss = t & 1023;
          dst[((bb * NH + hh) * SEQ + ss) * DH + dd] = f2bf(acc[i][j][r] + bv);
        }
      }
    }
  } else {
#pragma unroll
    for (int j = 0; j < 4; ++j) {
      const int col = n0 + wc * 64 + j * 16 + lr;
      const float bv = bias[col];
#pragma unroll
      for (int i = 0; i < 4; ++i)
#pragma unroll
        for (int r = 0; r < 4; ++r) {
          const int row = m0 + wr * 64 + i * 16 + lg * 4 + r;
          Cf[row * N + col] = acc[i][j][r] + bv;
        }
    }
  }
}

// ---------------- in-place partial rotary on Q and K ----------------
__global__ __launch_bounds__(256) void rope_kernel(unsigned short* __restrict__ Q,
                                                   unsigned short* __restrict__ K,
                                                   const float* __restrict__ cosb,
                                                   const float* __restrict__ sinb) {
  const int idx = blockIdx.x * 256 + threadIdx.x;  // B*H*S*16
  const int i = idx & 15;
  const int s = (idx >> 4) & 1023;
  const int bh = idx >> 14;
  const int b = bh >> 5;
  const int t = b * SEQ + s;
  const float c = cosb[t * 16 + i];
  const float sn = sinb[t * 16 + i];
  const int base = (bh * SEQ + s) * DH;
  float q1 = bf2f(Q[base + i]), q2 = bf2f(Q[base + 16 + i]);
  Q[base + i] = f2bf(q1 * c - q2 * sn);
  Q[base + 16 + i] = f2bf(q2 * c + q1 * sn);
  float k1 = bf2f(K[base + i]), k2 = bf2f(K[base + 16 + i]);
  K[base + i] = f2bf(k1 * c - k2 * sn);
  K[base + 16 + i] = f2bf(k2 * c + k1 * sn);
}

// ---------------- flash attention ----------------
// grid: (S/64, B*H). 256 threads = 4 waves; wave w owns q-rows [qt*64+w*16, +16).
__global__ __launch_bounds__(256) void attn_kernel(const unsigned short* __restrict__ Qb,
                                                   const unsigned short* __restrict__ Kb,
                                                   const unsigned short* __restrict__ Vb,
                                                   unsigned short* __restrict__ Ob) {
  __shared__ __align__(16) unsigned short Klds[64][104];  // D padded 80->96, stride 104
  __shared__ __align__(16) unsigned short Vt[80][72];     // V transposed [d][k]
  __shared__ __align__(16) unsigned short Plds[4][16][72];
  const int tid = threadIdx.x;
  const int lane = tid & 63, w = tid >> 6;
  const int lr = lane & 15, lg = lane >> 4;
  const int koff = lg * 8;
  const int qt = blockIdx.x, bh = blockIdx.y;
  const int h = bh & 31;
  const int base = bh * (SEQ * DH);

  // zero the K d-padding [80,96) once
  for (int e = tid; e < 64 * 16; e += 256) Klds[e >> 4][80 + (e & 15)] = 0;

  // Q fragments held in registers (A-operand rows = lane&15)
  const int qrow = qt * 64 + w * 16 + lr;
  bf16x8 qf[3];
#pragma unroll
  for (int c = 0; c < 3; ++c) {
    const int d = c * 32 + koff;
    if (d < DH)
      qf[c] = *(const bf16x8*)(Qb + base + qrow * DH + d);
    else
      qf[c] = (bf16x8)(__bf16)0.0f;
  }

  float m[4], l[4];
  f32x4 of[5];
#pragma unroll
  for (int r = 0; r < 4; ++r) {
    m[r] = -3.0e38f;
    l[r] = 0.0f;
  }
#pragma unroll
  for (int d = 0; d < 5; ++d) of[d] = (f32x4)0.0f;

  for (int kt = 0; kt <= qt; ++kt) {
    __syncthreads();
    // stage K tile (rows k, contiguous d), vectorized 16B
    for (int e = tid; e < 640; e += 256) {
      const int r = e / 10, dc = (e - r * 10) * 8;
      *(bf16x8*)&Klds[r][dc] = *(const bf16x8*)(Kb + base + (kt * 64 + r) * DH + dc);
    }
    // stage V transposed
    for (int e = tid; e < 5120; e += 256) {
      const int r = e / 80, d = e - r * 80;
      Vt[d][r] = Vb[base + (kt * 64 + r) * DH + d];
    }
    __syncthreads();

    // S = Q K^T  (wave computes 16x64)
    f32x4 sc[4];
#pragma unroll
    for (int cf = 0; cf < 4; ++cf) sc[cf] = (f32x4)0.0f;
#pragma unroll
    for (int c = 0; c < 3; ++c) {
#pragma unroll
      for (int cf = 0; cf < 4; ++cf) {
        bf16x8 kb = *(const bf16x8*)&Klds[cf * 16 + lr][c * 32 + koff];
        sc[cf] = __builtin_amdgcn_mfma_f32_16x16x32_bf16(qf[c], kb, sc[cf], 0, 0, 0);
      }
    }

    // scale + causal mask (C/D layout: row = lg*4+r, col = lr)
    const int rowg = qt * 64 + w * 16 + lg * 4;
#pragma unroll
    for (int cf = 0; cf < 4; ++cf) {
      const int colg = kt * 64 + cf * 16 + lr;
#pragma unroll
      for (int r = 0; r < 4; ++r) {
        float v = sc[cf][r] * SM_SCALE;
        if (colg > rowg + r) v = -1.0e30f;
        sc[cf][r] = v;
      }
    }

    // online softmax
    float al[4];
#pragma unroll
    for (int r = 0; r < 4; ++r) {
      float mx = fmaxf(fmaxf(sc[0][r], sc[1][r]), fmaxf(sc[2][r], sc[3][r]));
#pragma unroll
      for (int off = 1; off < 16; off <<= 1) mx = fmaxf(mx, __shfl_xor(mx, off, 64));
      const float mnew = fmaxf(m[r], mx);
      al[r] = __expf(m[r] - mnew);
      m[r] = mnew;
    }
    float ls[4] = {0.f, 0.f, 0.f, 0.f};
#pragma unroll
    for (int cf = 0; cf < 4; ++cf)
#pragma unroll
      for (int r = 0; r < 4; ++r) {
        const float p = __expf(sc[cf][r] - m[r]);
        sc[cf][r] = p;
        ls[r] += p;
      }
#pragma unroll
    for (int r = 0; r < 4; ++r) {
      float sv = ls[r];
#pragma unroll
      for (int off = 1; off < 16; off <<= 1) sv += __shfl_xor(sv, off, 64);
      l[r] = l[r] * al[r] + sv;
    }
#pragma unroll
    for (int d = 0; d < 5; ++d)
#pragma unroll
      for (int r = 0; r < 4; ++r) of[d][r] *= al[r];

    // P -> LDS (per-wave region), then PV
#pragma unroll
    for (int cf = 0; cf < 4; ++cf)
#pragma unroll
      for (int r = 0; r < 4; ++r)
        Plds[w][lg * 4 + r][cf * 16 + lr] = f2bf(sc[cf][r]);

#pragma unroll
    for (int kc = 0; kc < 2; ++kc) {
      bf16x8 pa = *(const bf16x8*)&Plds[w][lr][kc * 32 + koff];
#pragma unroll
      for (int d = 0; d < 5; ++d) {
        bf16x8 vb = *(const bf16x8*)&Vt[d * 16 + lr][kc * 32 + koff];
        of[d] = __builtin_amdgcn_mfma_f32_16x16x32_bf16(pa, vb, of[d], 0, 0, 0);
      }
    }
  }

  // epilogue: normalize and write [T][HID] bf16
  const int t = (bh >> 5) * SEQ + qt * 64 + w * 16 + lg * 4;
#pragma unroll
  for (int r = 0; r < 4; ++r) {
    const float rl = 1.0f / l[r];
#pragma unroll
    for (int d = 0; d < 5; ++d)
      Ob[(t + r) * HID + h * DH + d * 16 + lr] = f2bf(of[d][r] * rl);
  }
}

// ---------------- launch ----------------
extern "C" void kernel_launch(void* const* d_in, const int* in_sizes, int n_in,
                              void* d_out, int out_size, void* d_ws, size_t ws_size,
                              hipStream_t stream) {
  const float* hs = (const float*)d_in[0];
  const float* cosb = (const float*)d_in[1];
  const float* sinb = (const float*)d_in[2];
  const float* w_qkv = (const float*)d_in[3];
  const float* b_qkv = (const float*)d_in[4];
  const float* w_dense = (const float*)d_in[5];
  const float* b_dense = (const float*)d_in[6];
  float* out = (float*)d_out;
  char* ws = (char*)d_ws;

  // workspace layout (total ~123.2 MB)
  unsigned short* hsb = (unsigned short*)(ws + 0);           // 21.0 MB (T*HID bf16)
  unsigned short* aob = (unsigned short*)(ws + 0);           // alias (attn out)
  unsigned short* wqb = (unsigned short*)(ws + 20971520);    // 39.3 MB
  unsigned short* wdb = (unsigned short*)(ws + 20971520);    // alias (after gemm1)
  unsigned short* Qb = (unsigned short*)(ws + 60293120);     // 21.0 MB
  unsigned short* Kb = (unsigned short*)(ws + 81264640);     // 21.0 MB
  unsigned short* Vb = (unsigned short*)(ws + 102236160);    // 21.0 MB

  cvt_kernel<<<2048, 256, 0, stream>>>(hs, hsb, (NT * HID) / 4);
  cvt_kernel<<<2048, 256, 0, stream>>>(w_qkv, wqb, (NQKV * HID) / 4);
  gemm_kernel<0><<<dim3(NQKV / 128, NT / 128), 256, 0, stream>>>(
      hsb, wqb, b_qkv, Qb, Kb, Vb, nullptr, NT, NQKV, HID);
  cvt_kernel<<<2048, 256, 0, stream>>>(w_dense, wdb, (HID * HID) / 4);
  rope_kernel<<<(NB * NH * SEQ * 16) / 256, 256, 0, stream>>>(Qb, Kb, cosb, sinb);
  attn_kernel<<<dim3(SEQ / 64, NB * NH), 256, 0, stream>>>(Qb, Kb, Vb, aob);
  gemm_kernel<1><<<dim3(HID / 128, NT / 128), 256, 0, stream>>>(
      aob, wdb, b_dense, nullptr, nullptr, nullptr, out, NT, HID, HID);
}

// Round 2
// 568.312 us; speedup vs baseline: 1.0143x; 1.0143x over previous
//
#include <hip/hip_runtime.h>

typedef __attribute__((ext_vector_type(8))) __bf16 bf16x8;
typedef __attribute__((ext_vector_type(4))) float f32x4;

#define NH 32
#define DH 80
#define SEQ 1024
#define NB 4
#define NT 4096
#define HID 2560
#define NQKV 7680
#define SM_SCALE 0.11180339887498948f

static __device__ __forceinline__ unsigned short f2bf(float f) {
  unsigned u = __builtin_bit_cast(unsigned, f);
  u += 0x7fffu + ((u >> 16) & 1u);
  return (unsigned short)(u >> 16);
}
static __device__ __forceinline__ float bf2f(unsigned short s) {
  unsigned u = (unsigned)s << 16;
  return __builtin_bit_cast(float, u);
}

typedef __attribute__((address_space(1))) const unsigned int as1_uint;
typedef __attribute__((address_space(3))) unsigned int as3_uint;
static __device__ __forceinline__ void gload16(const void* g, void* l) {
  __builtin_amdgcn_global_load_lds((as1_uint*)g, (as3_uint*)l, 16, 0, 0);
}

// ---------------- fp32 -> bf16 convert (vectorized) ----------------
__global__ __launch_bounds__(256) void cvt_kernel(const float* __restrict__ in,
                                                  unsigned short* __restrict__ out,
                                                  int n4) {
  const float4* __restrict__ in4 = (const float4*)in;
  ushort4* __restrict__ out4 = (ushort4*)out;
  for (int i = blockIdx.x * blockDim.x + threadIdx.x; i < n4;
       i += gridDim.x * blockDim.x) {
    float4 v = in4[i];
    ushort4 o;
    o.x = f2bf(v.x);
    o.y = f2bf(v.y);
    o.z = f2bf(v.z);
    o.w = f2bf(v.w);
    out4[i] = o;
  }
}

// ---------------- bf16 MFMA GEMM: C[M][N] = A[M][K] @ B[N][K]^T + bias ------
// m97 structure: 128x128 tile, BK=64, global_load_lds(16B) staging into
// st-swizzled LDS (byte ^= (row&7)<<4) via pre-swizzled global source.
// EPI 0: scatter q/k/v (bf16) into [B][H][S][D] buffers.  EPI 1: fp32 C.
template <int EPI>
__global__ __launch_bounds__(256) void gemm_kernel(
    const unsigned short* __restrict__ A, const unsigned short* __restrict__ Bm,
    const float* __restrict__ bias, unsigned short* __restrict__ Cq,
    unsigned short* __restrict__ Ck, unsigned short* __restrict__ Cv,
    float* __restrict__ Cf, int M, int N, int K) {
  __shared__ __align__(16) unsigned short As[8192];  // 128 rows x 64 k (swizzled)
  __shared__ __align__(16) unsigned short Bs[8192];
  const int tid = threadIdx.x;
  const int lane = tid & 63, w = tid >> 6;
  const int wr = w >> 1, wc = w & 1;
  const int lr = lane & 15, lg = lane >> 4;

  // XCD-aware bijective block swizzle (nwg % 8 == 0 for both call sites)
  const int nwg = gridDim.x * gridDim.y;
  int bid = blockIdx.y * gridDim.x + blockIdx.x;
  bid = (bid & 7) * (nwg >> 3) + (bid >> 3);
  const int n0 = (bid % gridDim.x) * 128;
  const int m0 = (bid / gridDim.x) * 128;

  // Per-lane pre-swizzled global sources. Chunk c = w*4+i covers LDS bytes
  // [c*1024, c*1024+1024); lane l supplies the element whose UNswizzled
  // offset is u = off ^ (((off>>7)&7)<<4)  (involution; bits 4-6 ^= row bits 0-2).
  const unsigned short* asrc[4];
  const unsigned short* bsrc[4];
#pragma unroll
  for (int i = 0; i < 4; ++i) {
    const int off = (w * 4 + i) * 1024 + lane * 16;
    const int u = off ^ (((off >> 7) & 7) << 4);
    const int row = u >> 7, col = (u & 127) >> 1;
    asrc[i] = A + (size_t)(m0 + row) * K + col;
    bsrc[i] = Bm + (size_t)(n0 + row) * K + col;
  }

  f32x4 acc[4][4];
#pragma unroll
  for (int i = 0; i < 4; ++i)
#pragma unroll
    for (int j = 0; j < 4; ++j) acc[i][j] = (f32x4)0.0f;

  for (int k0 = 0; k0 < K; k0 += 64) {
    __syncthreads();
#pragma unroll
    for (int i = 0; i < 4; ++i) {
      gload16(asrc[i] + k0, (char*)As + (w * 4 + i) * 1024);
      gload16(bsrc[i] + k0, (char*)Bs + (w * 4 + i) * 1024);
    }
    __syncthreads();
#pragma unroll
    for (int ks = 0; ks < 2; ++ks) {
      bf16x8 af[4], bf[4];
#pragma unroll
      for (int i = 0; i < 4; ++i) {
        const int row = wr * 64 + i * 16 + lr;
        const int ub = row * 128 + ks * 64 + lg * 16;
        af[i] = *(const bf16x8*)((const char*)As + (ub ^ ((row & 7) << 4)));
      }
#pragma unroll
      for (int j = 0; j < 4; ++j) {
        const int row = wc * 64 + j * 16 + lr;
        const int ub = row * 128 + ks * 64 + lg * 16;
        bf[j] = *(const bf16x8*)((const char*)Bs + (ub ^ ((row & 7) << 4)));
      }
#pragma unroll
      for (int i = 0; i < 4; ++i)
#pragma unroll
        for (int j = 0; j < 4; ++j)
          acc[i][j] =
              __builtin_amdgcn_mfma_f32_16x16x32_bf16(af[i], bf[j], acc[i][j], 0, 0, 0);
    }
  }

  if (EPI == 0) {
#pragma unroll
    for (int j = 0; j < 4; ++j) {
      const int col = n0 + wc * 64 + j * 16 + lr;
      const int sec = col / HID;  // 0=q 1=k 2=v (uniform within 16-col frag)
      const int rem = col - sec * HID;
      const int hh = rem / DH;
      const int dd = rem - hh * DH;
      unsigned short* dst = sec == 0 ? Cq : (sec == 1 ? Ck : Cv);
      const float bv = bias[col];
#pragma unroll
      for (int i = 0; i < 4; ++i) {
#pragma unroll
        for (int r = 0; r < 4; ++r) {
          const int t = m0 + wr * 64 + i * 16 + lg * 4 + r;
          const int bb = t >> 10, ss = t & 1023;
          dst[((bb * NH + hh) * SEQ + ss) * DH + dd] = f2bf(acc[i][j][r] + bv);
        }
      }
    }
  } else {
#pragma unroll
    for (int j = 0; j < 4; ++j) {
      const int col = n0 + wc * 64 + j * 16 + lr;
      const float bv = bias[col];
#pragma unroll
      for (int i = 0; i < 4; ++i)
#pragma unroll
        for (int r = 0; r < 4; ++r) {
          const int row = m0 + wr * 64 + i * 16 + lg * 4 + r;
          Cf[row * N + col] = acc[i][j][r] + bv;
        }
    }
  }
}

// ---------------- in-place partial rotary on Q and K ----------------
__global__ __launch_bounds__(256) void rope_kernel(unsigned short* __restrict__ Q,
                                                   unsigned short* __restrict__ K,
                                                   const float* __restrict__ cosb,
                                                   const float* __restrict__ sinb) {
  const int idx = blockIdx.x * 256 + threadIdx.x;  // B*H*S*16
  const int i = idx & 15;
  const int s = (idx >> 4) & 1023;
  const int bh = idx >> 14;
  const int b = bh >> 5;
  const int t = b * SEQ + s;
  const float c = cosb[t * 16 + i];
  const float sn = sinb[t * 16 + i];
  const int base = (bh * SEQ + s) * DH;
  float q1 = bf2f(Q[base + i]), q2 = bf2f(Q[base + 16 + i]);
  Q[base + i] = f2bf(q1 * c - q2 * sn);
  Q[base + 16 + i] = f2bf(q2 * c + q1 * sn);
  float k1 = bf2f(K[base + i]), k2 = bf2f(K[base + 16 + i]);
  K[base + i] = f2bf(k1 * c - k2 * sn);
  K[base + 16 + i] = f2bf(k2 * c + k1 * sn);
}

// ---------------- flash attention ----------------
// grid: (S/64, B*H). 256 threads = 4 waves; wave w owns q-rows [qt*64+w*16, +16).
__global__ __launch_bounds__(256) void attn_kernel(const unsigned short* __restrict__ Qb,
                                                   const unsigned short* __restrict__ Kb,
                                                   const unsigned short* __restrict__ Vb,
                                                   unsigned short* __restrict__ Ob) {
  __shared__ __align__(16) unsigned short Klds[64][104];  // D padded 80->96, stride 104
  __shared__ __align__(16) unsigned short Vt[80][72];     // V transposed [d][k]
  __shared__ __align__(16) unsigned short Plds[4][16][72];
  const int tid = threadIdx.x;
  const int lane = tid & 63, w = tid >> 6;
  const int lr = lane & 15, lg = lane >> 4;
  const int koff = lg * 8;
  const int qt = blockIdx.x, bh = blockIdx.y;
  const int h = bh & 31;
  const int base = bh * (SEQ * DH);

  // zero the K d-padding [80,96) once
  for (int e = tid; e < 64 * 16; e += 256) Klds[e >> 4][80 + (e & 15)] = 0;

  // Q fragments held in registers (A-operand rows = lane&15)
  const int qrow = qt * 64 + w * 16 + lr;
  bf16x8 qf[3];
#pragma unroll
  for (int c = 0; c < 3; ++c) {
    const int d = c * 32 + koff;
    if (d < DH)
      qf[c] = *(const bf16x8*)(Qb + base + qrow * DH + d);
    else
      qf[c] = (bf16x8)(__bf16)0.0f;
  }

  float m[4], l[4];
  f32x4 of[5];
#pragma unroll
  for (int r = 0; r < 4; ++r) {
    m[r] = -3.0e38f;
    l[r] = 0.0f;
  }
#pragma unroll
  for (int d = 0; d < 5; ++d) of[d] = (f32x4)0.0f;

  for (int kt = 0; kt <= qt; ++kt) {
    __syncthreads();
    // stage K tile (rows k, contiguous d), vectorized 16B
    for (int e = tid; e < 640; e += 256) {
      const int r = e / 10, dc = (e - r * 10) * 8;
      *(bf16x8*)&Klds[r][dc] = *(const bf16x8*)(Kb + base + (kt * 64 + r) * DH + dc);
    }
    // stage V transposed
    for (int e = tid; e < 5120; e += 256) {
      const int r = e / 80, d = e - r * 80;
      Vt[d][r] = Vb[base + (kt * 64 + r) * DH + d];
    }
    __syncthreads();

    // S = Q K^T  (wave computes 16x64)
    f32x4 sc[4];
#pragma unroll
    for (int cf = 0; cf < 4; ++cf) sc[cf] = (f32x4)0.0f;
#pragma unroll
    for (int c = 0; c < 3; ++c) {
#pragma unroll
      for (int cf = 0; cf < 4; ++cf) {
        bf16x8 kb = *(const bf16x8*)&Klds[cf * 16 + lr][c * 32 + koff];
        sc[cf] = __builtin_amdgcn_mfma_f32_16x16x32_bf16(qf[c], kb, sc[cf], 0, 0, 0);
      }
    }

    // scale + causal mask (C/D layout: row = lg*4+r, col = lr)
    const int rowg = qt * 64 + w * 16 + lg * 4;
#pragma unroll
    for (int cf = 0; cf < 4; ++cf) {
      const int colg = kt * 64 + cf * 16 + lr;
#pragma unroll
      for (int r = 0; r < 4; ++r) {
        float v = sc[cf][r] * SM_SCALE;
        if (colg > rowg + r) v = -1.0e30f;
        sc[cf][r] = v;
      }
    }

    // online softmax
    float al[4];
#pragma unroll
    for (int r = 0; r < 4; ++r) {
      float mx = fmaxf(fmaxf(sc[0][r], sc[1][r]), fmaxf(sc[2][r], sc[3][r]));
#pragma unroll
      for (int off = 1; off < 16; off <<= 1) mx = fmaxf(mx, __shfl_xor(mx, off, 64));
      const float mnew = fmaxf(m[r], mx);
      al[r] = __expf(m[r] - mnew);
      m[r] = mnew;
    }
    float ls[4] = {0.f, 0.f, 0.f, 0.f};
#pragma unroll
    for (int cf = 0; cf < 4; ++cf)
#pragma unroll
      for (int r = 0; r < 4; ++r) {
        const float p = __expf(sc[cf][r] - m[r]);
        sc[cf][r] = p;
        ls[r] += p;
      }
#pragma unroll
    for (int r = 0; r < 4; ++r) {
      float sv = ls[r];
#pragma unroll
      for (int off = 1; off < 16; off <<= 1) sv += __shfl_xor(sv, off, 64);
      l[r] = l[r] * al[r] + sv;
    }
#pragma unroll
    for (int d = 0; d < 5; ++d)
#pragma unroll
      for (int r = 0; r < 4; ++r) of[d][r] *= al[r];

    // P -> LDS (per-wave region), then PV
#pragma unroll
    for (int cf = 0; cf < 4; ++cf)
#pragma unroll
      for (int r = 0; r < 4; ++r)
        Plds[w][lg * 4 + r][cf * 16 + lr] = f2bf(sc[cf][r]);

#pragma unroll
    for (int kc = 0; kc < 2; ++kc) {
      bf16x8 pa = *(const bf16x8*)&Plds[w][lr][kc * 32 + koff];
#pragma unroll
      for (int d = 0; d < 5; ++d) {
        bf16x8 vb = *(const bf16x8*)&Vt[d * 16 + lr][kc * 32 + koff];
        of[d] = __builtin_amdgcn_mfma_f32_16x16x32_bf16(pa, vb, of[d], 0, 0, 0);
      }
    }
  }

  // epilogue: normalize and write [T][HID] bf16
  const int t = (bh >> 5) * SEQ + qt * 64 + w * 16 + lg * 4;
#pragma unroll
  for (int r = 0; r < 4; ++r) {
    const float rl = 1.0f / l[r];
#pragma unroll
    for (int d = 0; d < 5; ++d)
      Ob[(t + r) * HID + h * DH + d * 16 + lr] = f2bf(of[d][r] * rl);
  }
}

// ---------------- launch ----------------
extern "C" void kernel_launch(void* const* d_in, const int* in_sizes, int n_in,
                              void* d_out, int out_size, void* d_ws, size_t ws_size,
                              hipStream_t stream) {
  const float* hs = (const float*)d_in[0];
  const float* cosb = (const float*)d_in[1];
  const float* sinb = (const float*)d_in[2];
  const float* w_qkv = (const float*)d_in[3];
  const float* b_qkv = (const float*)d_in[4];
  const float* w_dense = (const float*)d_in[5];
  const float* b_dense = (const float*)d_in[6];
  float* out = (float*)d_out;
  char* ws = (char*)d_ws;

  // workspace layout (total ~123.2 MB)
  unsigned short* hsb = (unsigned short*)(ws + 0);         // 21.0 MB (T*HID bf16)
  unsigned short* aob = (unsigned short*)(ws + 0);         // alias (attn out)
  unsigned short* wqb = (unsigned short*)(ws + 20971520);  // 39.3 MB
  unsigned short* wdb = (unsigned short*)(ws + 20971520);  // alias (after gemm1)
  unsigned short* Qb = (unsigned short*)(ws + 60293120);   // 21.0 MB
  unsigned short* Kb = (unsigned short*)(ws + 81264640);   // 21.0 MB
  unsigned short* Vb = (unsigned short*)(ws + 102236160);  // 21.0 MB

  cvt_kernel<<<2048, 256, 0, stream>>>(hs, hsb, (NT * HID) / 4);
  cvt_kernel<<<2048, 256, 0, stream>>>(w_qkv, wqb, (NQKV * HID) / 4);
  gemm_kernel<0><<<dim3(NQKV / 128, NT / 128), 256, 0, stream>>>(
      hsb, wqb, b_qkv, Qb, Kb, Vb, nullptr, NT, NQKV, HID);
  cvt_kernel<<<2048, 256, 0, stream>>>(w_dense, wdb, (HID * HID) / 4);
  rope_kernel<<<(NB * NH * SEQ * 16) / 256, 256, 0, stream>>>(Qb, Kb, cosb, sinb);
  attn_kernel<<<dim3(SEQ / 64, NB * NH), 256, 0, stream>>>(Qb, Kb, Vb, aob);
  gemm_kernel<1><<<dim3(HID / 128, NT / 128), 256, 0, stream>>>(
      aob, wdb, b_dense, nullptr, nullptr, nullptr, out, NT, HID, HID);
}

// Round 3
// 509.213 us; speedup vs baseline: 1.1320x; 1.1161x over previous
//
#include <hip/hip_runtime.h>

typedef __attribute__((ext_vector_type(8))) __bf16 bf16x8;
typedef __attribute__((ext_vector_type(4))) float f32x4;

#define NH 32
#define DH 80
#define SEQ 1024
#define NB 4
#define NT 4096
#define HID 2560
#define NQKV 7680
#define SM_SCALE 0.11180339887498948f

static __device__ __forceinline__ unsigned short f2bf(float f) {
  unsigned u = __builtin_bit_cast(unsigned, f);
  u += 0x7fffu + ((u >> 16) & 1u);
  return (unsigned short)(u >> 16);
}
static __device__ __forceinline__ float bf2f(unsigned short s) {
  unsigned u = (unsigned)s << 16;
  return __builtin_bit_cast(float, u);
}

typedef __attribute__((address_space(1))) const unsigned int as1_uint;
typedef __attribute__((address_space(3))) unsigned int as3_uint;
static __device__ __forceinline__ void gload16(const void* g, void* l) {
  __builtin_amdgcn_global_load_lds((as1_uint*)g, (as3_uint*)l, 16, 0, 0);
}

// ---------------- fp32 -> bf16 convert (vectorized) ----------------
__global__ __launch_bounds__(256) void cvt_kernel(const float* __restrict__ in,
                                                  unsigned short* __restrict__ out,
                                                  int n4) {
  const float4* __restrict__ in4 = (const float4*)in;
  ushort4* __restrict__ out4 = (ushort4*)out;
  for (int i = blockIdx.x * blockDim.x + threadIdx.x; i < n4;
       i += gridDim.x * blockDim.x) {
    float4 v = in4[i];
    ushort4 o;
    o.x = f2bf(v.x);
    o.y = f2bf(v.y);
    o.z = f2bf(v.z);
    o.w = f2bf(v.w);
    out4[i] = o;
  }
}

// ------------- 256x256-tile pipelined bf16 GEMM: C = A @ B^T + bias -------------
// 512 threads = 8 waves (2M x 4N); BK=32; 4-deep LDS ring; staging 3 tiles
// ahead via global_load_lds(16B) with pre-swizzled global source; counted
// vmcnt(8) at tile boundaries (never drains in steady state).
// LDS swizzle: byte ^= ((row>>1)&3)<<4  (bits 4-5 ^ row bits 1-2, involution).
// EPI 0: scatter q/k/v (bf16) into [B][H][S][D].  EPI 1: fp32 C.
template <int EPI>
__global__ __launch_bounds__(512, 2) void gemm256_kernel(
    const unsigned short* __restrict__ A, const unsigned short* __restrict__ Bm,
    const float* __restrict__ bias, unsigned short* __restrict__ Cq,
    unsigned short* __restrict__ Ck, unsigned short* __restrict__ Cv,
    float* __restrict__ Cf, int M, int N, int K) {
  __shared__ __align__(16) unsigned short As[4][8192];  // 4 x [256 rows][32 k]
  __shared__ __align__(16) unsigned short Bs[4][8192];
  const int tid = threadIdx.x;
  const int lane = tid & 63, w = tid >> 6;
  const int wm = w >> 2, wn = w & 3;
  const int lr = lane & 15, lg = lane >> 4;

  // XCD-aware bijective block swizzle (nwg % 8 == 0 at both call sites)
  const int gx = gridDim.x;
  const int nwg = gx * gridDim.y;
  int bid = blockIdx.y * gx + blockIdx.x;
  bid = (bid & 7) * (nwg >> 3) + (bid >> 3);
  const int n0 = (bid % gx) * 256;
  const int m0 = (bid / gx) * 256;

  // Per-lane pre-swizzled global sources. Chunk ch covers LDS bytes
  // [ch*8192, +8192) (rows 128*ch..128*ch+127); this thread's 16B lands at
  // off = ch*8192 + tid*16; it must carry the element whose unswizzled
  // offset is u = off ^ ((off>>7)&3)<<4.
  const unsigned short* asrc[2];
  const unsigned short* bsrc[2];
#pragma unroll
  for (int i = 0; i < 2; ++i) {
    const int off = i * 8192 + tid * 16;
    const int u = off ^ (((off >> 7) & 3) << 4);
    const int row = u >> 6, col = (u & 63) >> 1;
    asrc[i] = A + (size_t)(m0 + row) * K + col;
    bsrc[i] = Bm + (size_t)(n0 + row) * K + col;
  }

  const int NTl = K >> 5;  // K-tiles of 32

#define STAGE_A(buf, kt, ch) \
  gload16(asrc[ch] + (kt) * 32, (char*)&As[buf][0] + (ch) * 8192 + w * 1024)
#define STAGE_B(buf, kt, ch) \
  gload16(bsrc[ch] + (kt) * 32, (char*)&Bs[buf][0] + (ch) * 8192 + w * 1024)

  // prologue: stage tiles 0,1,2 into ring slots 0,1,2 (12 gloads in flight)
  STAGE_A(0, 0, 0); STAGE_A(0, 0, 1); STAGE_B(0, 0, 0); STAGE_B(0, 0, 1);
  STAGE_A(1, 1, 0); STAGE_A(1, 1, 1); STAGE_B(1, 1, 0); STAGE_B(1, 1, 1);
  STAGE_A(2, 2, 0); STAGE_A(2, 2, 1); STAGE_B(2, 2, 0); STAGE_B(2, 2, 1);

  f32x4 acc[8][4];
#pragma unroll
  for (int i = 0; i < 8; ++i)
#pragma unroll
    for (int j = 0; j < 4; ++j) acc[i][j] = (f32x4)0.0f;

  for (int t = 0; t < NTl; ++t) {
    const int c = t & 3;
    const char* ap = (const char*)&As[c][0];
    const char* bp = (const char*)&Bs[c][0];
    // tile-start: own loads for tile t landed (2 later tiles' 8 loads stay
    // in flight); only the last two tiles drain 4 -> 0.
    if (t + 2 < NTl)
      asm volatile("s_waitcnt vmcnt(8)" ::: "memory");
    else if (t + 1 < NTl)
      asm volatile("s_waitcnt vmcnt(4)" ::: "memory");
    else
      asm volatile("s_waitcnt vmcnt(0)" ::: "memory");
    __builtin_amdgcn_s_barrier();

    bf16x8 breg[4], areg[4], areg2[4];
    // ---- phase 0: read B(all) + A(mf0-3); prefetch A-chunks of tile t+3 ----
#pragma unroll
    for (int nf = 0; nf < 4; ++nf) {
      const int row = wn * 64 + nf * 16 + lr;
      const int ub = row * 64 + lg * 16;
      breg[nf] = *(const bf16x8*)(bp + (ub ^ (((row >> 1) & 3) << 4)));
    }
#pragma unroll
    for (int mf = 0; mf < 4; ++mf) {
      const int row = wm * 128 + mf * 16 + lr;
      const int ub = row * 64 + lg * 16;
      areg[mf] = *(const bf16x8*)(ap + (ub ^ (((row >> 1) & 3) << 4)));
    }
    if (t + 3 < NTl) {
      STAGE_A((t + 3) & 3, t + 3, 0);
      STAGE_A((t + 3) & 3, t + 3, 1);
    }
    __builtin_amdgcn_s_barrier();
    __builtin_amdgcn_s_setprio(1);
#pragma unroll
    for (int mf = 0; mf < 4; ++mf)
#pragma unroll
      for (int nf = 0; nf < 4; ++nf)
        acc[mf][nf] = __builtin_amdgcn_mfma_f32_16x16x32_bf16(areg[mf], breg[nf],
                                                              acc[mf][nf], 0, 0, 0);
    __builtin_amdgcn_s_setprio(0);
    // ---- phase 1: read A(mf4-7); prefetch B-chunks of tile t+3 ----
#pragma unroll
    for (int mf = 0; mf < 4; ++mf) {
      const int row = wm * 128 + (mf + 4) * 16 + lr;
      const int ub = row * 64 + lg * 16;
      areg2[mf] = *(const bf16x8*)(ap + (ub ^ (((row >> 1) & 3) << 4)));
    }
    if (t + 3 < NTl) {
      STAGE_B((t + 3) & 3, t + 3, 0);
      STAGE_B((t + 3) & 3, t + 3, 1);
    }
    __builtin_amdgcn_s_barrier();
    __builtin_amdgcn_s_setprio(1);
#pragma unroll
    for (int mf = 0; mf < 4; ++mf)
#pragma unroll
      for (int nf = 0; nf < 4; ++nf)
        acc[mf + 4][nf] = __builtin_amdgcn_mfma_f32_16x16x32_bf16(
            areg2[mf], breg[nf], acc[mf + 4][nf], 0, 0, 0);
    __builtin_amdgcn_s_setprio(0);
  }
#undef STAGE_A
#undef STAGE_B

  if (EPI == 0) {
#pragma unroll
    for (int nf = 0; nf < 4; ++nf) {
      const int col = n0 + wn * 64 + nf * 16 + lr;
      const int sec = col / HID;  // 0=q 1=k 2=v (uniform within 16-col frag)
      const int rem = col - sec * HID;
      const int hh = rem / DH;
      const int dd = rem - hh * DH;
      unsigned short* dst = sec == 0 ? Cq : (sec == 1 ? Ck : Cv);
      const float bv = bias[col];
#pragma unroll
      for (int mf = 0; mf < 8; ++mf) {
#pragma unroll
        for (int r = 0; r < 4; ++r) {
          const int tr = m0 + wm * 128 + mf * 16 + lg * 4 + r;
          const int bb = tr >> 10, ss = tr & 1023;
          dst[((bb * NH + hh) * SEQ + ss) * DH + dd] = f2bf(acc[mf][nf][r] + bv);
        }
      }
    }
  } else {
#pragma unroll
    for (int nf = 0; nf < 4; ++nf) {
      const int col = n0 + wn * 64 + nf * 16 + lr;
      const float bv = bias[col];
#pragma unroll
      for (int mf = 0; mf < 8; ++mf)
#pragma unroll
        for (int r = 0; r < 4; ++r) {
          const int row = m0 + wm * 128 + mf * 16 + lg * 4 + r;
          Cf[row * N + col] = acc[mf][nf][r] + bv;
        }
    }
  }
}

// ---------------- in-place partial rotary on Q and K ----------------
__global__ __launch_bounds__(256) void rope_kernel(unsigned short* __restrict__ Q,
                                                   unsigned short* __restrict__ K,
                                                   const float* __restrict__ cosb,
                                                   const float* __restrict__ sinb) {
  const int idx = blockIdx.x * 256 + threadIdx.x;  // B*H*S*16
  const int i = idx & 15;
  const int s = (idx >> 4) & 1023;
  const int bh = idx >> 14;
  const int b = bh >> 5;
  const int t = b * SEQ + s;
  const float c = cosb[t * 16 + i];
  const float sn = sinb[t * 16 + i];
  const int base = (bh * SEQ + s) * DH;
  float q1 = bf2f(Q[base + i]), q2 = bf2f(Q[base + 16 + i]);
  Q[base + i] = f2bf(q1 * c - q2 * sn);
  Q[base + 16 + i] = f2bf(q2 * c + q1 * sn);
  float k1 = bf2f(K[base + i]), k2 = bf2f(K[base + 16 + i]);
  K[base + i] = f2bf(k1 * c - k2 * sn);
  K[base + 16 + i] = f2bf(k2 * c + k1 * sn);
}

// ---------------- flash attention ----------------
// grid: (S/64, B*H). 256 threads = 4 waves; wave w owns q-rows [qt*64+w*16, +16).
__global__ __launch_bounds__(256) void attn_kernel(const unsigned short* __restrict__ Qb,
                                                   const unsigned short* __restrict__ Kb,
                                                   const unsigned short* __restrict__ Vb,
                                                   unsigned short* __restrict__ Ob) {
  __shared__ __align__(16) unsigned short Klds[64][104];  // D padded 80->96, stride 104
  __shared__ __align__(16) unsigned short Vt[80][72];     // V transposed [d][k]
  __shared__ __align__(16) unsigned short Plds[4][16][72];
  const int tid = threadIdx.x;
  const int lane = tid & 63, w = tid >> 6;
  const int lr = lane & 15, lg = lane >> 4;
  const int koff = lg * 8;
  const int qt = blockIdx.x, bh = blockIdx.y;
  const int h = bh & 31;
  const int base = bh * (SEQ * DH);

  // zero the K d-padding [80,96) once
  for (int e = tid; e < 64 * 16; e += 256) Klds[e >> 4][80 + (e & 15)] = 0;

  // Q fragments held in registers (A-operand rows = lane&15)
  const int qrow = qt * 64 + w * 16 + lr;
  bf16x8 qf[3];
#pragma unroll
  for (int c = 0; c < 3; ++c) {
    const int d = c * 32 + koff;
    if (d < DH)
      qf[c] = *(const bf16x8*)(Qb + base + qrow * DH + d);
    else
      qf[c] = (bf16x8)(__bf16)0.0f;
  }

  float m[4], l[4];
  f32x4 of[5];
#pragma unroll
  for (int r = 0; r < 4; ++r) {
    m[r] = -3.0e38f;
    l[r] = 0.0f;
  }
#pragma unroll
  for (int d = 0; d < 5; ++d) of[d] = (f32x4)0.0f;

  for (int kt = 0; kt <= qt; ++kt) {
    __syncthreads();
    // stage K tile (rows k, contiguous d), vectorized 16B
    for (int e = tid; e < 640; e += 256) {
      const int r = e / 10, dc = (e - r * 10) * 8;
      *(bf16x8*)&Klds[r][dc] = *(const bf16x8*)(Kb + base + (kt * 64 + r) * DH + dc);
    }
    // stage V transposed
    for (int e = tid; e < 5120; e += 256) {
      const int r = e / 80, d = e - r * 80;
      Vt[d][r] = Vb[base + (kt * 64 + r) * DH + d];
    }
    __syncthreads();

    // S = Q K^T  (wave computes 16x64)
    f32x4 sc[4];
#pragma unroll
    for (int cf = 0; cf < 4; ++cf) sc[cf] = (f32x4)0.0f;
#pragma unroll
    for (int c = 0; c < 3; ++c) {
#pragma unroll
      for (int cf = 0; cf < 4; ++cf) {
        bf16x8 kb = *(const bf16x8*)&Klds[cf * 16 + lr][c * 32 + koff];
        sc[cf] = __builtin_amdgcn_mfma_f32_16x16x32_bf16(qf[c], kb, sc[cf], 0, 0, 0);
      }
    }

    // scale + causal mask (C/D layout: row = lg*4+r, col = lr)
    const int rowg = qt * 64 + w * 16 + lg * 4;
#pragma unroll
    for (int cf = 0; cf < 4; ++cf) {
      const int colg = kt * 64 + cf * 16 + lr;
#pragma unroll
      for (int r = 0; r < 4; ++r) {
        float v = sc[cf][r] * SM_SCALE;
        if (colg > rowg + r) v = -1.0e30f;
        sc[cf][r] = v;
      }
    }

    // online softmax
    float al[4];
#pragma unroll
    for (int r = 0; r < 4; ++r) {
      float mx = fmaxf(fmaxf(sc[0][r], sc[1][r]), fmaxf(sc[2][r], sc[3][r]));
#pragma unroll
      for (int off = 1; off < 16; off <<= 1) mx = fmaxf(mx, __shfl_xor(mx, off, 64));
      const float mnew = fmaxf(m[r], mx);
      al[r] = __expf(m[r] - mnew);
      m[r] = mnew;
    }
    float ls[4] = {0.f, 0.f, 0.f, 0.f};
#pragma unroll
    for (int cf = 0; cf < 4; ++cf)
#pragma unroll
      for (int r = 0; r < 4; ++r) {
        const float p = __expf(sc[cf][r] - m[r]);
        sc[cf][r] = p;
        ls[r] += p;
      }
#pragma unroll
    for (int r = 0; r < 4; ++r) {
      float sv = ls[r];
#pragma unroll
      for (int off = 1; off < 16; off <<= 1) sv += __shfl_xor(sv, off, 64);
      l[r] = l[r] * al[r] + sv;
    }
#pragma unroll
    for (int d = 0; d < 5; ++d)
#pragma unroll
      for (int r = 0; r < 4; ++r) of[d][r] *= al[r];

    // P -> LDS (per-wave region), then PV
#pragma unroll
    for (int cf = 0; cf < 4; ++cf)
#pragma unroll
      for (int r = 0; r < 4; ++r)
        Plds[w][lg * 4 + r][cf * 16 + lr] = f2bf(sc[cf][r]);

#pragma unroll
    for (int kc = 0; kc < 2; ++kc) {
      bf16x8 pa = *(const bf16x8*)&Plds[w][lr][kc * 32 + koff];
#pragma unroll
      for (int d = 0; d < 5; ++d) {
        bf16x8 vb = *(const bf16x8*)&Vt[d * 16 + lr][kc * 32 + koff];
        of[d] = __builtin_amdgcn_mfma_f32_16x16x32_bf16(pa, vb, of[d], 0, 0, 0);
      }
    }
  }

  // epilogue: normalize and write [T][HID] bf16
  const int t = (bh >> 5) * SEQ + qt * 64 + w * 16 + lg * 4;
#pragma unroll
  for (int r = 0; r < 4; ++r) {
    const float rl = 1.0f / l[r];
#pragma unroll
    for (int d = 0; d < 5; ++d)
      Ob[(t + r) * HID + h * DH + d * 16 + lr] = f2bf(of[d][r] * rl);
  }
}

// ---------------- launch ----------------
extern "C" void kernel_launch(void* const* d_in, const int* in_sizes, int n_in,
                              void* d_out, int out_size, void* d_ws, size_t ws_size,
                              hipStream_t stream) {
  const float* hs = (const float*)d_in[0];
  const float* cosb = (const float*)d_in[1];
  const float* sinb = (const float*)d_in[2];
  const float* w_qkv = (const float*)d_in[3];
  const float* b_qkv = (const float*)d_in[4];
  const float* w_dense = (const float*)d_in[5];
  const float* b_dense = (const float*)d_in[6];
  float* out = (float*)d_out;
  char* ws = (char*)d_ws;

  // workspace layout (total ~123.2 MB)
  unsigned short* hsb = (unsigned short*)(ws + 0);         // 21.0 MB (T*HID bf16)
  unsigned short* aob = (unsigned short*)(ws + 0);         // alias (attn out)
  unsigned short* wqb = (unsigned short*)(ws + 20971520);  // 39.3 MB
  unsigned short* wdb = (unsigned short*)(ws + 20971520);  // alias (after gemm1)
  unsigned short* Qb = (unsigned short*)(ws + 60293120);   // 21.0 MB
  unsigned short* Kb = (unsigned short*)(ws + 81264640);   // 21.0 MB
  unsigned short* Vb = (unsigned short*)(ws + 102236160);  // 21.0 MB

  cvt_kernel<<<2048, 256, 0, stream>>>(hs, hsb, (NT * HID) / 4);
  cvt_kernel<<<2048, 256, 0, stream>>>(w_qkv, wqb, (NQKV * HID) / 4);
  gemm256_kernel<0><<<dim3(NQKV / 256, NT / 256), 512, 0, stream>>>(
      hsb, wqb, b_qkv, Qb, Kb, Vb, nullptr, NT, NQKV, HID);
  cvt_kernel<<<2048, 256, 0, stream>>>(w_dense, wdb, (HID * HID) / 4);
  rope_kernel<<<(NB * NH * SEQ * 16) / 256, 256, 0, stream>>>(Qb, Kb, cosb, sinb);
  attn_kernel<<<dim3(SEQ / 64, NB * NH), 256, 0, stream>>>(Qb, Kb, Vb, aob);
  gemm256_kernel<1><<<dim3(HID / 256, NT / 256), 512, 0, stream>>>(
      aob, wdb, b_dense, nullptr, nullptr, nullptr, out, NT, HID, HID);
}

// Round 4
// 490.672 us; speedup vs baseline: 1.1748x; 1.0378x over previous
//
#include <hip/hip_runtime.h>

typedef __attribute__((ext_vector_type(8))) __bf16 bf16x8;
typedef __attribute__((ext_vector_type(4))) float f32x4;

#define NH 32
#define DH 80
#define SEQ 1024
#define NB 4
#define NT 4096
#define HID 2560
#define NQKV 7680
#define SM_SCALE 0.11180339887498948f

static __device__ __forceinline__ unsigned short f2bf(float f) {
  unsigned u = __builtin_bit_cast(unsigned, f);
  u += 0x7fffu + ((u >> 16) & 1u);
  return (unsigned short)(u >> 16);
}
static __device__ __forceinline__ float bf2f(unsigned short s) {
  unsigned u = (unsigned)s << 16;
  return __builtin_bit_cast(float, u);
}

typedef __attribute__((address_space(1))) const unsigned int as1_uint;
typedef __attribute__((address_space(3))) unsigned int as3_uint;
static __device__ __forceinline__ void gload16(const void* g, void* l) {
  __builtin_amdgcn_global_load_lds((as1_uint*)g, (as3_uint*)l, 16, 0, 0);
}

// ---------------- fp32 -> bf16 convert (vectorized) ----------------
__global__ __launch_bounds__(256) void cvt_kernel(const float* __restrict__ in,
                                                  unsigned short* __restrict__ out,
                                                  int n4) {
  const float4* __restrict__ in4 = (const float4*)in;
  ushort4* __restrict__ out4 = (ushort4*)out;
  for (int i = blockIdx.x * blockDim.x + threadIdx.x; i < n4;
       i += gridDim.x * blockDim.x) {
    float4 v = in4[i];
    ushort4 o;
    o.x = f2bf(v.x);
    o.y = f2bf(v.y);
    o.z = f2bf(v.z);
    o.w = f2bf(v.w);
    out4[i] = o;
  }
}

// ------------- 256x256-tile pipelined bf16 GEMM: C = A @ B^T + bias -------------
// 512 threads = 8 waves (2M x 4N); BK=32; 4-deep LDS ring; staging 3 tiles
// ahead via global_load_lds(16B) with pre-swizzled global source; counted
// vmcnt(8) at tile boundaries (never drains in steady state).
// EPI 0: scatter q/k into [B][H][S][D]; V into [B][H][D][S] (transposed, so
//        attention needs no in-kernel V transpose).  EPI 1: fp32 C.
template <int EPI>
__global__ __launch_bounds__(512, 2) void gemm256_kernel(
    const unsigned short* __restrict__ A, const unsigned short* __restrict__ Bm,
    const float* __restrict__ bias, unsigned short* __restrict__ Cq,
    unsigned short* __restrict__ Ck, unsigned short* __restrict__ Cv,
    float* __restrict__ Cf, int M, int N, int K) {
  __shared__ __align__(16) unsigned short As[4][8192];  // 4 x [256 rows][32 k]
  __shared__ __align__(16) unsigned short Bs[4][8192];
  const int tid = threadIdx.x;
  const int lane = tid & 63, w = tid >> 6;
  const int wm = w >> 2, wn = w & 3;
  const int lr = lane & 15, lg = lane >> 4;

  // XCD-aware bijective block swizzle (nwg % 8 == 0 at both call sites)
  const int gx = gridDim.x;
  const int nwg = gx * gridDim.y;
  int bid = blockIdx.y * gx + blockIdx.x;
  bid = (bid & 7) * (nwg >> 3) + (bid >> 3);
  const int n0 = (bid % gx) * 256;
  const int m0 = (bid / gx) * 256;

  // Per-lane pre-swizzled global sources (LDS swizzle: byte ^= ((row>>1)&3)<<4).
  const unsigned short* asrc[2];
  const unsigned short* bsrc[2];
#pragma unroll
  for (int i = 0; i < 2; ++i) {
    const int off = i * 8192 + tid * 16;
    const int u = off ^ (((off >> 7) & 3) << 4);
    const int row = u >> 6, col = (u & 63) >> 1;
    asrc[i] = A + (size_t)(m0 + row) * K + col;
    bsrc[i] = Bm + (size_t)(n0 + row) * K + col;
  }

  const int NTl = K >> 5;  // K-tiles of 32

#define STAGE_A(buf, kt, ch) \
  gload16(asrc[ch] + (kt) * 32, (char*)&As[buf][0] + (ch) * 8192 + w * 1024)
#define STAGE_B(buf, kt, ch) \
  gload16(bsrc[ch] + (kt) * 32, (char*)&Bs[buf][0] + (ch) * 8192 + w * 1024)

  // prologue: stage tiles 0,1,2 into ring slots 0,1,2 (12 gloads in flight)
  STAGE_A(0, 0, 0); STAGE_A(0, 0, 1); STAGE_B(0, 0, 0); STAGE_B(0, 0, 1);
  STAGE_A(1, 1, 0); STAGE_A(1, 1, 1); STAGE_B(1, 1, 0); STAGE_B(1, 1, 1);
  STAGE_A(2, 2, 0); STAGE_A(2, 2, 1); STAGE_B(2, 2, 0); STAGE_B(2, 2, 1);

  f32x4 acc[8][4];
#pragma unroll
  for (int i = 0; i < 8; ++i)
#pragma unroll
    for (int j = 0; j < 4; ++j) acc[i][j] = (f32x4)0.0f;

  for (int t = 0; t < NTl; ++t) {
    const int c = t & 3;
    const char* ap = (const char*)&As[c][0];
    const char* bp = (const char*)&Bs[c][0];
    if (t + 2 < NTl)
      asm volatile("s_waitcnt vmcnt(8)" ::: "memory");
    else if (t + 1 < NTl)
      asm volatile("s_waitcnt vmcnt(4)" ::: "memory");
    else
      asm volatile("s_waitcnt vmcnt(0)" ::: "memory");
    __builtin_amdgcn_s_barrier();

    bf16x8 breg[4], areg[4], areg2[4];
    // ---- phase 0: read B(all) + A(mf0-3); prefetch A-chunks of tile t+3 ----
#pragma unroll
    for (int nf = 0; nf < 4; ++nf) {
      const int row = wn * 64 + nf * 16 + lr;
      const int ub = row * 64 + lg * 16;
      breg[nf] = *(const bf16x8*)(bp + (ub ^ (((row >> 1) & 3) << 4)));
    }
#pragma unroll
    for (int mf = 0; mf < 4; ++mf) {
      const int row = wm * 128 + mf * 16 + lr;
      const int ub = row * 64 + lg * 16;
      areg[mf] = *(const bf16x8*)(ap + (ub ^ (((row >> 1) & 3) << 4)));
    }
    if (t + 3 < NTl) {
      STAGE_A((t + 3) & 3, t + 3, 0);
      STAGE_A((t + 3) & 3, t + 3, 1);
    }
    __builtin_amdgcn_s_barrier();
    __builtin_amdgcn_s_setprio(1);
#pragma unroll
    for (int mf = 0; mf < 4; ++mf)
#pragma unroll
      for (int nf = 0; nf < 4; ++nf)
        acc[mf][nf] = __builtin_amdgcn_mfma_f32_16x16x32_bf16(areg[mf], breg[nf],
                                                              acc[mf][nf], 0, 0, 0);
    __builtin_amdgcn_s_setprio(0);
    // ---- phase 1: read A(mf4-7); prefetch B-chunks of tile t+3 ----
#pragma unroll
    for (int mf = 0; mf < 4; ++mf) {
      const int row = wm * 128 + (mf + 4) * 16 + lr;
      const int ub = row * 64 + lg * 16;
      areg2[mf] = *(const bf16x8*)(ap + (ub ^ (((row >> 1) & 3) << 4)));
    }
    if (t + 3 < NTl) {
      STAGE_B((t + 3) & 3, t + 3, 0);
      STAGE_B((t + 3) & 3, t + 3, 1);
    }
    __builtin_amdgcn_s_barrier();
    __builtin_amdgcn_s_setprio(1);
#pragma unroll
    for (int mf = 0; mf < 4; ++mf)
#pragma unroll
      for (int nf = 0; nf < 4; ++nf)
        acc[mf + 4][nf] = __builtin_amdgcn_mfma_f32_16x16x32_bf16(
            areg2[mf], breg[nf], acc[mf + 4][nf], 0, 0, 0);
    __builtin_amdgcn_s_setprio(0);
  }
#undef STAGE_A
#undef STAGE_B

  if (EPI == 0) {
#pragma unroll
    for (int nf = 0; nf < 4; ++nf) {
      const int col = n0 + wn * 64 + nf * 16 + lr;
      const int sec = col / HID;  // 0=q 1=k 2=v (uniform within 16-col frag)
      const int rem = col - sec * HID;
      const int hh = rem / DH;
      const int dd = rem - hh * DH;
      unsigned short* dst = sec == 0 ? Cq : (sec == 1 ? Ck : Cv);
      const float bv = bias[col];
#pragma unroll
      for (int mf = 0; mf < 8; ++mf) {
#pragma unroll
        for (int r = 0; r < 4; ++r) {
          const int tr = m0 + wm * 128 + mf * 16 + lg * 4 + r;
          const int bb = tr >> 10, ss = tr & 1023;
          const size_t idx =
              (sec == 2) ? ((size_t)(bb * NH + hh) * DH + dd) * SEQ + ss
                         : ((size_t)(bb * NH + hh) * SEQ + ss) * DH + dd;
          dst[idx] = f2bf(acc[mf][nf][r] + bv);
        }
      }
    }
  } else {
#pragma unroll
    for (int nf = 0; nf < 4; ++nf) {
      const int col = n0 + wn * 64 + nf * 16 + lr;
      const float bv = bias[col];
#pragma unroll
      for (int mf = 0; mf < 8; ++mf)
#pragma unroll
        for (int r = 0; r < 4; ++r) {
          const int row = m0 + wm * 128 + mf * 16 + lg * 4 + r;
          Cf[row * N + col] = acc[mf][nf][r] + bv;
        }
    }
  }
}

// ---------------- in-place partial rotary on Q and K ----------------
__global__ __launch_bounds__(256) void rope_kernel(unsigned short* __restrict__ Q,
                                                   unsigned short* __restrict__ K,
                                                   const float* __restrict__ cosb,
                                                   const float* __restrict__ sinb) {
  const int idx = blockIdx.x * 256 + threadIdx.x;  // B*H*S*16
  const int i = idx & 15;
  const int s = (idx >> 4) & 1023;
  const int bh = idx >> 14;
  const int b = bh >> 5;
  const int t = b * SEQ + s;
  const float c = cosb[t * 16 + i];
  const float sn = sinb[t * 16 + i];
  const int base = (bh * SEQ + s) * DH;
  float q1 = bf2f(Q[base + i]), q2 = bf2f(Q[base + 16 + i]);
  Q[base + i] = f2bf(q1 * c - q2 * sn);
  Q[base + 16 + i] = f2bf(q2 * c + q1 * sn);
  float k1 = bf2f(K[base + i]), k2 = bf2f(K[base + 16 + i]);
  K[base + i] = f2bf(k1 * c - k2 * sn);
  K[base + 16 + i] = f2bf(k2 * c + k1 * sn);
}

// ---------------- flash attention ----------------
// grid: (S/128, B*H). 512 threads = 8 waves; wave w owns q-rows
// [qt*128 + w*16, +16). V arrives already transposed ([B][H][D][S]), so
// staging is pure 16B coalesced loads + 16B LDS writes (no transpose).
__global__ __launch_bounds__(512) void attn_kernel(const unsigned short* __restrict__ Qb,
                                                   const unsigned short* __restrict__ Kb,
                                                   const unsigned short* __restrict__ Vg,
                                                   unsigned short* __restrict__ Ob) {
  __shared__ __align__(16) unsigned short Klds[64][104];  // D padded 80->96, stride 104
  __shared__ __align__(16) unsigned short Vt[80][72];     // V^T tile [d][k]
  __shared__ __align__(16) unsigned short Plds[8][16][72];
  const int tid = threadIdx.x;
  const int lane = tid & 63, w = tid >> 6;
  const int lr = lane & 15, lg = lane >> 4;
  const int koff = lg * 8;
  const int qt = blockIdx.x, bh = blockIdx.y;
  const int h = bh & 31;
  const int base = bh * (SEQ * DH);   // Q,K: [B][H][S][D]
  const int vbase = bh * (DH * SEQ);  // V:   [B][H][D][S]

  // zero the K d-padding [80,96) once
  for (int e = tid; e < 64 * 16; e += 512) Klds[e >> 4][80 + (e & 15)] = 0;

  // Q fragments held in registers (A-operand rows = lane&15)
  const int rowbase = qt * 128 + w * 16;
  const int qrow = rowbase + lr;
  bf16x8 qf[3];
#pragma unroll
  for (int c = 0; c < 3; ++c) {
    const int d = c * 32 + koff;
    if (d < DH)
      qf[c] = *(const bf16x8*)(Qb + base + qrow * DH + d);
    else
      qf[c] = (bf16x8)(__bf16)0.0f;
  }

  float m[4], l[4];
  f32x4 of[5];
#pragma unroll
  for (int r = 0; r < 4; ++r) {
    m[r] = -3.0e38f;
    l[r] = 0.0f;
  }
#pragma unroll
  for (int d = 0; d < 5; ++d) of[d] = (f32x4)0.0f;

  const int ktmax = 2 * qt + 1;
  for (int kt = 0; kt <= ktmax; ++kt) {
    __syncthreads();
    // stage K tile (rows k, contiguous d), vectorized 16B
    for (int e = tid; e < 640; e += 512) {
      const int r = e / 10, dc = (e - r * 10) * 8;
      *(bf16x8*)&Klds[r][dc] = *(const bf16x8*)(Kb + base + (kt * 64 + r) * DH + dc);
    }
    // stage V^T tile: row d, cols kt*64..+63 — fully vectorized, no transpose
    for (int e = tid; e < 640; e += 512) {
      const int d = e >> 3, sc = (e & 7) * 8;
      *(bf16x8*)&Vt[d][sc] = *(const bf16x8*)(Vg + vbase + d * SEQ + kt * 64 + sc);
    }
    __syncthreads();

    if (kt * 64 > rowbase + 15) continue;  // tile fully masked for this wave

    // S = Q K^T  (wave computes 16x64)
    f32x4 sc[4];
#pragma unroll
    for (int cf = 0; cf < 4; ++cf) sc[cf] = (f32x4)0.0f;
#pragma unroll
    for (int c = 0; c < 3; ++c) {
#pragma unroll
      for (int cf = 0; cf < 4; ++cf) {
        bf16x8 kb = *(const bf16x8*)&Klds[cf * 16 + lr][c * 32 + koff];
        sc[cf] = __builtin_amdgcn_mfma_f32_16x16x32_bf16(qf[c], kb, sc[cf], 0, 0, 0);
      }
    }

    // scale + causal mask (C/D layout: row = lg*4+r, col = lr)
    const int rowg = rowbase + lg * 4;
#pragma unroll
    for (int cf = 0; cf < 4; ++cf) {
      const int colg = kt * 64 + cf * 16 + lr;
#pragma unroll
      for (int r = 0; r < 4; ++r) {
        float v = sc[cf][r] * SM_SCALE;
        if (colg > rowg + r) v = -1.0e30f;
        sc[cf][r] = v;
      }
    }

    // online softmax
    float al[4];
#pragma unroll
    for (int r = 0; r < 4; ++r) {
      float mx = fmaxf(fmaxf(sc[0][r], sc[1][r]), fmaxf(sc[2][r], sc[3][r]));
#pragma unroll
      for (int off = 1; off < 16; off <<= 1) mx = fmaxf(mx, __shfl_xor(mx, off, 64));
      const float mnew = fmaxf(m[r], mx);
      al[r] = __expf(m[r] - mnew);
      m[r] = mnew;
    }
    float ls[4] = {0.f, 0.f, 0.f, 0.f};
#pragma unroll
    for (int cf = 0; cf < 4; ++cf)
#pragma unroll
      for (int r = 0; r < 4; ++r) {
        const float p = __expf(sc[cf][r] - m[r]);
        sc[cf][r] = p;
        ls[r] += p;
      }
#pragma unroll
    for (int r = 0; r < 4; ++r) {
      float sv = ls[r];
#pragma unroll
      for (int off = 1; off < 16; off <<= 1) sv += __shfl_xor(sv, off, 64);
      l[r] = l[r] * al[r] + sv;
    }
#pragma unroll
    for (int d = 0; d < 5; ++d)
#pragma unroll
      for (int r = 0; r < 4; ++r) of[d][r] *= al[r];

    // P -> LDS (per-wave region), then PV
#pragma unroll
    for (int cf = 0; cf < 4; ++cf)
#pragma unroll
      for (int r = 0; r < 4; ++r)
        Plds[w][lg * 4 + r][cf * 16 + lr] = f2bf(sc[cf][r]);

#pragma unroll
    for (int kc = 0; kc < 2; ++kc) {
      bf16x8 pa = *(const bf16x8*)&Plds[w][lr][kc * 32 + koff];
#pragma unroll
      for (int d = 0; d < 5; ++d) {
        bf16x8 vb = *(const bf16x8*)&Vt[d * 16 + lr][kc * 32 + koff];
        of[d] = __builtin_amdgcn_mfma_f32_16x16x32_bf16(pa, vb, of[d], 0, 0, 0);
      }
    }
  }

  // epilogue: normalize and write [T][HID] bf16
  const int t = (bh >> 5) * SEQ + rowbase + lg * 4;
#pragma unroll
  for (int r = 0; r < 4; ++r) {
    const float rl = 1.0f / l[r];
#pragma unroll
    for (int d = 0; d < 5; ++d)
      Ob[(t + r) * HID + h * DH + d * 16 + lr] = f2bf(of[d][r] * rl);
  }
}

// ---------------- launch ----------------
extern "C" void kernel_launch(void* const* d_in, const int* in_sizes, int n_in,
                              void* d_out, int out_size, void* d_ws, size_t ws_size,
                              hipStream_t stream) {
  const float* hs = (const float*)d_in[0];
  const float* cosb = (const float*)d_in[1];
  const float* sinb = (const float*)d_in[2];
  const float* w_qkv = (const float*)d_in[3];
  const float* b_qkv = (const float*)d_in[4];
  const float* w_dense = (const float*)d_in[5];
  const float* b_dense = (const float*)d_in[6];
  float* out = (float*)d_out;
  char* ws = (char*)d_ws;

  // workspace layout (total ~123.2 MB)
  unsigned short* hsb = (unsigned short*)(ws + 0);         // 21.0 MB (T*HID bf16)
  unsigned short* aob = (unsigned short*)(ws + 0);         // alias (attn out)
  unsigned short* wqb = (unsigned short*)(ws + 20971520);  // 39.3 MB
  unsigned short* wdb = (unsigned short*)(ws + 20971520);  // alias (after gemm1)
  unsigned short* Qb = (unsigned short*)(ws + 60293120);   // 21.0 MB
  unsigned short* Kb = (unsigned short*)(ws + 81264640);   // 21.0 MB
  unsigned short* Vb = (unsigned short*)(ws + 102236160);  // 21.0 MB ([B][H][D][S])

  cvt_kernel<<<2048, 256, 0, stream>>>(hs, hsb, (NT * HID) / 4);
  cvt_kernel<<<2048, 256, 0, stream>>>(w_qkv, wqb, (NQKV * HID) / 4);
  gemm256_kernel<0><<<dim3(NQKV / 256, NT / 256), 512, 0, stream>>>(
      hsb, wqb, b_qkv, Qb, Kb, Vb, nullptr, NT, NQKV, HID);
  cvt_kernel<<<2048, 256, 0, stream>>>(w_dense, wdb, (HID * HID) / 4);
  rope_kernel<<<(NB * NH * SEQ * 16) / 256, 256, 0, stream>>>(Qb, Kb, cosb, sinb);
  attn_kernel<<<dim3(SEQ / 128, NB * NH), 512, 0, stream>>>(Qb, Kb, Vb, aob);
  gemm256_kernel<1><<<dim3(HID / 256, NT / 256), 512, 0, stream>>>(
      aob, wdb, b_dense, nullptr, nullptr, nullptr, out, NT, HID, HID);
}

// Round 6
// 488.352 us; speedup vs baseline: 1.1804x; 1.0048x over previous
//
#include <hip/hip_runtime.h>

typedef __attribute__((ext_vector_type(8))) __bf16 bf16x8;
typedef __attribute__((ext_vector_type(4))) float f32x4;

#define NH 32
#define DH 80
#define SEQ 1024
#define NB 4
#define NT 4096
#define HID 2560
#define NQKV 7680
#define SM_SCALE 0.11180339887498948f

static __device__ __forceinline__ unsigned short f2bf(float f) {
  unsigned u = __builtin_bit_cast(unsigned, f);
  u += 0x7fffu + ((u >> 16) & 1u);
  return (unsigned short)(u >> 16);
}
static __device__ __forceinline__ float bf2f(unsigned short s) {
  unsigned u = (unsigned)s << 16;
  return __builtin_bit_cast(float, u);
}

typedef __attribute__((address_space(1))) const unsigned int as1_uint;
typedef __attribute__((address_space(3))) unsigned int as3_uint;
static __device__ __forceinline__ void gload16(const void* g, void* l) {
  __builtin_amdgcn_global_load_lds((as1_uint*)g, (as3_uint*)l, 16, 0, 0);
}

// ---------------- fp32 -> bf16 convert (vectorized) ----------------
__global__ __launch_bounds__(256) void cvt_kernel(const float* __restrict__ in,
                                                  unsigned short* __restrict__ out,
                                                  int n4) {
  const float4* __restrict__ in4 = (const float4*)in;
  ushort4* __restrict__ out4 = (ushort4*)out;
  for (int i = blockIdx.x * blockDim.x + threadIdx.x; i < n4;
       i += gridDim.x * blockDim.x) {
    float4 v = in4[i];
    ushort4 o;
    o.x = f2bf(v.x);
    o.y = f2bf(v.y);
    o.z = f2bf(v.z);
    o.w = f2bf(v.w);
    out4[i] = o;
  }
}

// ------------- 256x256 4-phase pipelined bf16 GEMM: C = A @ B^T + bias -------
// BK=64, 2-deep dbuf (128 KiB), 8 waves (2M x 4N). Per K-tile: 4 phases
// {ds_read quadrant frags || stage next tile -> barrier -> setprio(1)
// 16 MFMA setprio(0) -> barrier}. Staging: all A-halves at phase 0, all
// B-halves at phase 1 (phases 2-3 pure compute). Tile boundary: UNIFORM
// s_waitcnt vmcnt(0) (wave-own count + barrier => block-wide guarantee;
// outstanding loads were issued >=2 phases earlier, so the wait is covered).
// LDS swizzle: byte ^= (row&7)<<4 via pre-swizzled global source (writes
// linear, reads swizzled). EPI 0: scatter q/k [B][H][S][D], v [B][H][D][S].
// EPI 1: fp32 C.
template <int EPI>
__global__ __launch_bounds__(512, 2) void gemm8p_kernel(
    const unsigned short* __restrict__ A, const unsigned short* __restrict__ Bm,
    const float* __restrict__ bias, unsigned short* __restrict__ Cq,
    unsigned short* __restrict__ Ck, unsigned short* __restrict__ Cv,
    float* __restrict__ Cf, int M, int N, int K) {
  __shared__ __align__(16) unsigned short As[2][16384];  // [buf][256 rows][64 k]
  __shared__ __align__(16) unsigned short Bs[2][16384];
  const int tid = threadIdx.x;
  const int lane = tid & 63, w = tid >> 6;
  const int wm = w >> 2, wn = w & 3;
  const int lr = lane & 15, lg = lane >> 4;

  // XCD-aware bijective block swizzle (nwg % 8 == 0 at both call sites)
  const int gx = gridDim.x;
  const int nwg = gx * gridDim.y;
  int bid = blockIdx.y * gx + blockIdx.x;
  bid = (bid & 7) * (nwg >> 3) + (bid >> 3);
  const int n0 = (bid % gx) * 256;
  const int m0 = (bid / gx) * 256;

  // Pre-swizzled staging sources: half h2 (rows 128*h2..+127), chunk j.
  // LDS image is st-swizzled; gload dest stays linear (rule #21).
  const unsigned short* asrc[2][2];
  const unsigned short* bsrc[2][2];
#pragma unroll
  for (int h2 = 0; h2 < 2; ++h2)
#pragma unroll
    for (int j = 0; j < 2; ++j) {
      const int off = h2 * 16384 + j * 8192 + tid * 16;
      const int u = off ^ (((off >> 7) & 7) << 4);
      const int row = u >> 7, col = (u & 127) >> 1;
      asrc[h2][j] = A + (size_t)(m0 + row) * K + col;
      bsrc[h2][j] = Bm + (size_t)(n0 + row) * K + col;
    }

  const int NK = K >> 6;  // K-tiles of 64 (2560 -> 40)

#define STG_A(buf, kt, h2)                                          \
  {                                                                 \
    gload16(asrc[h2][0] + (size_t)(kt)*64,                          \
            (char*)&As[buf][0] + (h2)*16384 + w * 1024);            \
    gload16(asrc[h2][1] + (size_t)(kt)*64,                          \
            (char*)&As[buf][0] + (h2)*16384 + 8192 + w * 1024);     \
  }
#define STG_B(buf, kt, h2)                                          \
  {                                                                 \
    gload16(bsrc[h2][0] + (size_t)(kt)*64,                          \
            (char*)&Bs[buf][0] + (h2)*16384 + w * 1024);            \
    gload16(bsrc[h2][1] + (size_t)(kt)*64,                          \
            (char*)&Bs[buf][0] + (h2)*16384 + 8192 + w * 1024);     \
  }
// Fragment read from swizzled LDS: row-major [256][64], byte ^= (row&7)<<4.
#define FRAG(basep, row, ks)                                        \
  (*(const bf16x8*)((const char*)(basep) +                          \
                    (((row)*128 + (ks)*64 + lg * 16) ^ (((row)&7) << 4))))

  f32x4 acc[8][4];
#pragma unroll
  for (int i = 0; i < 8; ++i)
#pragma unroll
    for (int j = 0; j < 4; ++j) acc[i][j] = (f32x4)0.0f;

  // prologue: stage tile 0 into buf0, uniform drain, barrier
  STG_A(0, 0, 0);
  STG_A(0, 0, 1);
  STG_B(0, 0, 0);
  STG_B(0, 0, 1);
  asm volatile("s_waitcnt vmcnt(0)" ::: "memory");
  __builtin_amdgcn_s_barrier();

  for (int t = 0; t < NK; ++t) {
    const int buf = t & 1, nb = buf ^ 1;
    const unsigned short* ab = &As[buf][0];
    const unsigned short* bb = &Bs[buf][0];
    const bool pf = (t + 1) < NK;
    bf16x8 bfr[4], afr[4];

    // ---- phase 0: ks=0, m-half 0; stage next A (both halves) ----
#pragma unroll
    for (int nf = 0; nf < 4; ++nf) bfr[nf] = FRAG(bb, wn * 64 + nf * 16 + lr, 0);
#pragma unroll
    for (int mf = 0; mf < 4; ++mf) afr[mf] = FRAG(ab, wm * 128 + mf * 16 + lr, 0);
    if (pf) {
      STG_A(nb, t + 1, 0);
      STG_A(nb, t + 1, 1);
    }
    __builtin_amdgcn_s_barrier();
    __builtin_amdgcn_s_setprio(1);
#pragma unroll
    for (int mf = 0; mf < 4; ++mf)
#pragma unroll
      for (int nf = 0; nf < 4; ++nf)
        acc[mf][nf] =
            __builtin_amdgcn_mfma_f32_16x16x32_bf16(afr[mf], bfr[nf], acc[mf][nf], 0, 0, 0);
    __builtin_amdgcn_s_setprio(0);
    __builtin_amdgcn_s_barrier();

    // ---- phase 1: ks=0, m-half 1 (B frags reused); stage next B ----
#pragma unroll
    for (int mf = 0; mf < 4; ++mf)
      afr[mf] = FRAG(ab, wm * 128 + 64 + mf * 16 + lr, 0);
    if (pf) {
      STG_B(nb, t + 1, 0);
      STG_B(nb, t + 1, 1);
    }
    __builtin_amdgcn_s_barrier();
    __builtin_amdgcn_s_setprio(1);
#pragma unroll
    for (int mf = 0; mf < 4; ++mf)
#pragma unroll
      for (int nf = 0; nf < 4; ++nf)
        acc[mf + 4][nf] = __builtin_amdgcn_mfma_f32_16x16x32_bf16(
            afr[mf], bfr[nf], acc[mf + 4][nf], 0, 0, 0);
    __builtin_amdgcn_s_setprio(0);
    __builtin_amdgcn_s_barrier();

    // ---- phase 2: ks=1, m-half 0 (pure compute) ----
#pragma unroll
    for (int nf = 0; nf < 4; ++nf) bfr[nf] = FRAG(bb, wn * 64 + nf * 16 + lr, 1);
#pragma unroll
    for (int mf = 0; mf < 4; ++mf) afr[mf] = FRAG(ab, wm * 128 + mf * 16 + lr, 1);
    __builtin_amdgcn_s_barrier();
    __builtin_amdgcn_s_setprio(1);
#pragma unroll
    for (int mf = 0; mf < 4; ++mf)
#pragma unroll
      for (int nf = 0; nf < 4; ++nf)
        acc[mf][nf] =
            __builtin_amdgcn_mfma_f32_16x16x32_bf16(afr[mf], bfr[nf], acc[mf][nf], 0, 0, 0);
    __builtin_amdgcn_s_setprio(0);
    __builtin_amdgcn_s_barrier();

    // ---- phase 3: ks=1, m-half 1 (pure compute) ----
#pragma unroll
    for (int mf = 0; mf < 4; ++mf)
      afr[mf] = FRAG(ab, wm * 128 + 64 + mf * 16 + lr, 1);
    __builtin_amdgcn_s_barrier();
    __builtin_amdgcn_s_setprio(1);
#pragma unroll
    for (int mf = 0; mf < 4; ++mf)
#pragma unroll
      for (int nf = 0; nf < 4; ++nf)
        acc[mf + 4][nf] = __builtin_amdgcn_mfma_f32_16x16x32_bf16(
            afr[mf], bfr[nf], acc[mf + 4][nf], 0, 0, 0);
    __builtin_amdgcn_s_setprio(0);
    // tile boundary: UNIFORM wait (loads issued >=2 phases ago), then barrier
    if (pf) asm volatile("s_waitcnt vmcnt(0)" ::: "memory");
    __builtin_amdgcn_s_barrier();
  }
#undef STG_A
#undef STG_B
#undef FRAG

  if (EPI == 0) {
#pragma unroll
    for (int nf = 0; nf < 4; ++nf) {
      const int col = n0 + wn * 64 + nf * 16 + lr;
      const int sec = col / HID;  // 0=q 1=k 2=v (uniform within 16-col frag)
      const int rem = col - sec * HID;
      const int hh = rem / DH;
      const int dd = rem - hh * DH;
      unsigned short* dst = sec == 0 ? Cq : (sec == 1 ? Ck : Cv);
      const float bv = bias[col];
#pragma unroll
      for (int mf = 0; mf < 8; ++mf) {
#pragma unroll
        for (int r = 0; r < 4; ++r) {
          const int tr = m0 + wm * 128 + mf * 16 + lg * 4 + r;
          const int bb2 = tr >> 10, ss = tr & 1023;
          const size_t idx =
              (sec == 2) ? ((size_t)(bb2 * NH + hh) * DH + dd) * SEQ + ss
                         : ((size_t)(bb2 * NH + hh) * SEQ + ss) * DH + dd;
          dst[idx] = f2bf(acc[mf][nf][r] + bv);
        }
      }
    }
  } else {
#pragma unroll
    for (int nf = 0; nf < 4; ++nf) {
      const int col = n0 + wn * 64 + nf * 16 + lr;
      const float bv = bias[col];
#pragma unroll
      for (int mf = 0; mf < 8; ++mf)
#pragma unroll
        for (int r = 0; r < 4; ++r) {
          const int row = m0 + wm * 128 + mf * 16 + lg * 4 + r;
          Cf[row * N + col] = acc[mf][nf][r] + bv;
        }
    }
  }
}

// ---------------- in-place partial rotary on Q and K ----------------
__global__ __launch_bounds__(256) void rope_kernel(unsigned short* __restrict__ Q,
                                                   unsigned short* __restrict__ K,
                                                   const float* __restrict__ cosb,
                                                   const float* __restrict__ sinb) {
  const int idx = blockIdx.x * 256 + threadIdx.x;  // B*H*S*16
  const int i = idx & 15;
  const int s = (idx >> 4) & 1023;
  const int bh = idx >> 14;
  const int b = bh >> 5;
  const int t = b * SEQ + s;
  const float c = cosb[t * 16 + i];
  const float sn = sinb[t * 16 + i];
  const int base = (bh * SEQ + s) * DH;
  float q1 = bf2f(Q[base + i]), q2 = bf2f(Q[base + 16 + i]);
  Q[base + i] = f2bf(q1 * c - q2 * sn);
  Q[base + 16 + i] = f2bf(q2 * c + q1 * sn);
  float k1 = bf2f(K[base + i]), k2 = bf2f(K[base + 16 + i]);
  K[base + i] = f2bf(k1 * c - k2 * sn);
  K[base + 16 + i] = f2bf(k2 * c + k1 * sn);
}

// ---------------- flash attention ----------------
// grid: (S/128, B*H). 512 threads = 8 waves; wave w owns q-rows
// [qt*128 + w*16, +16). V arrives already transposed ([B][H][D][S]).
__global__ __launch_bounds__(512) void attn_kernel(const unsigned short* __restrict__ Qb,
                                                   const unsigned short* __restrict__ Kb,
                                                   const unsigned short* __restrict__ Vg,
                                                   unsigned short* __restrict__ Ob) {
  __shared__ __align__(16) unsigned short Klds[64][104];  // D padded 80->96, stride 104
  __shared__ __align__(16) unsigned short Vt[80][72];     // V^T tile [d][k]
  __shared__ __align__(16) unsigned short Plds[8][16][72];
  const int tid = threadIdx.x;
  const int lane = tid & 63, w = tid >> 6;
  const int lr = lane & 15, lg = lane >> 4;
  const int koff = lg * 8;
  const int qt = blockIdx.x, bh = blockIdx.y;
  const int h = bh & 31;
  const int base = bh * (SEQ * DH);   // Q,K: [B][H][S][D]
  const int vbase = bh * (DH * SEQ);  // V:   [B][H][D][S]

  for (int e = tid; e < 64 * 16; e += 512) Klds[e >> 4][80 + (e & 15)] = 0;

  const int rowbase = qt * 128 + w * 16;
  const int qrow = rowbase + lr;
  bf16x8 qf[3];
#pragma unroll
  for (int c = 0; c < 3; ++c) {
    const int d = c * 32 + koff;
    if (d < DH)
      qf[c] = *(const bf16x8*)(Qb + base + qrow * DH + d);
    else
      qf[c] = (bf16x8)(__bf16)0.0f;
  }

  float m[4], l[4];
  f32x4 of[5];
#pragma unroll
  for (int r = 0; r < 4; ++r) {
    m[r] = -3.0e38f;
    l[r] = 0.0f;
  }
#pragma unroll
  for (int d = 0; d < 5; ++d) of[d] = (f32x4)0.0f;

  const int ktmax = 2 * qt + 1;
  for (int kt = 0; kt <= ktmax; ++kt) {
    __syncthreads();
    for (int e = tid; e < 640; e += 512) {
      const int r = e / 10, dc = (e - r * 10) * 8;
      *(bf16x8*)&Klds[r][dc] = *(const bf16x8*)(Kb + base + (kt * 64 + r) * DH + dc);
    }
    for (int e = tid; e < 640; e += 512) {
      const int d = e >> 3, sc = (e & 7) * 8;
      *(bf16x8*)&Vt[d][sc] = *(const bf16x8*)(Vg + vbase + d * SEQ + kt * 64 + sc);
    }
    __syncthreads();

    if (kt * 64 > rowbase + 15) continue;

    f32x4 sc[4];
#pragma unroll
    for (int cf = 0; cf < 4; ++cf) sc[cf] = (f32x4)0.0f;
#pragma unroll
    for (int c = 0; c < 3; ++c) {
#pragma unroll
      for (int cf = 0; cf < 4; ++cf) {
        bf16x8 kb = *(const bf16x8*)&Klds[cf * 16 + lr][c * 32 + koff];
        sc[cf] = __builtin_amdgcn_mfma_f32_16x16x32_bf16(qf[c], kb, sc[cf], 0, 0, 0);
      }
    }

    const int rowg = rowbase + lg * 4;
#pragma unroll
    for (int cf = 0; cf < 4; ++cf) {
      const int colg = kt * 64 + cf * 16 + lr;
#pragma unroll
      for (int r = 0; r < 4; ++r) {
        float v = sc[cf][r] * SM_SCALE;
        if (colg > rowg + r) v = -1.0e30f;
        sc[cf][r] = v;
      }
    }

    float al[4];
#pragma unroll
    for (int r = 0; r < 4; ++r) {
      float mx = fmaxf(fmaxf(sc[0][r], sc[1][r]), fmaxf(sc[2][r], sc[3][r]));
#pragma unroll
      for (int off = 1; off < 16; off <<= 1) mx = fmaxf(mx, __shfl_xor(mx, off, 64));
      const float mnew = fmaxf(m[r], mx);
      al[r] = __expf(m[r] - mnew);
      m[r] = mnew;
    }
    float ls[4] = {0.f, 0.f, 0.f, 0.f};
#pragma unroll
    for (int cf = 0; cf < 4; ++cf)
#pragma unroll
      for (int r = 0; r < 4; ++r) {
        const float p = __expf(sc[cf][r] - m[r]);
        sc[cf][r] = p;
        ls[r] += p;
      }
#pragma unroll
    for (int r = 0; r < 4; ++r) {
      float sv = ls[r];
#pragma unroll
      for (int off = 1; off < 16; off <<= 1) sv += __shfl_xor(sv, off, 64);
      l[r] = l[r] * al[r] + sv;
    }
#pragma unroll
    for (int d = 0; d < 5; ++d)
#pragma unroll
      for (int r = 0; r < 4; ++r) of[d][r] *= al[r];

#pragma unroll
    for (int cf = 0; cf < 4; ++cf)
#pragma unroll
      for (int r = 0; r < 4; ++r)
        Plds[w][lg * 4 + r][cf * 16 + lr] = f2bf(sc[cf][r]);

#pragma unroll
    for (int kc = 0; kc < 2; ++kc) {
      bf16x8 pa = *(const bf16x8*)&Plds[w][lr][kc * 32 + koff];
#pragma unroll
      for (int d = 0; d < 5; ++d) {
        bf16x8 vb = *(const bf16x8*)&Vt[d * 16 + lr][kc * 32 + koff];
        of[d] = __builtin_amdgcn_mfma_f32_16x16x32_bf16(pa, vb, of[d], 0, 0, 0);
      }
    }
  }

  const int t = (bh >> 5) * SEQ + rowbase + lg * 4;
#pragma unroll
  for (int r = 0; r < 4; ++r) {
    const float rl = 1.0f / l[r];
#pragma unroll
    for (int d = 0; d < 5; ++d)
      Ob[(t + r) * HID + h * DH + d * 16 + lr] = f2bf(of[d][r] * rl);
  }
}

// ---------------- launch ----------------
extern "C" void kernel_launch(void* const* d_in, const int* in_sizes, int n_in,
                              void* d_out, int out_size, void* d_ws, size_t ws_size,
                              hipStream_t stream) {
  const float* hs = (const float*)d_in[0];
  const float* cosb = (const float*)d_in[1];
  const float* sinb = (const float*)d_in[2];
  const float* w_qkv = (const float*)d_in[3];
  const float* b_qkv = (const float*)d_in[4];
  const float* w_dense = (const float*)d_in[5];
  const float* b_dense = (const float*)d_in[6];
  float* out = (float*)d_out;
  char* ws = (char*)d_ws;

  // workspace layout (total ~123.2 MB)
  unsigned short* hsb = (unsigned short*)(ws + 0);         // 21.0 MB (T*HID bf16)
  unsigned short* aob = (unsigned short*)(ws + 0);         // alias (attn out)
  unsigned short* wqb = (unsigned short*)(ws + 20971520);  // 39.3 MB
  unsigned short* wdb = (unsigned short*)(ws + 20971520);  // alias (after gemm1)
  unsigned short* Qb = (unsigned short*)(ws + 60293120);   // 21.0 MB
  unsigned short* Kb = (unsigned short*)(ws + 81264640);   // 21.0 MB
  unsigned short* Vb = (unsigned short*)(ws + 102236160);  // 21.0 MB ([B][H][D][S])

  cvt_kernel<<<2048, 256, 0, stream>>>(hs, hsb, (NT * HID) / 4);
  cvt_kernel<<<2048, 256, 0, stream>>>(w_qkv, wqb, (NQKV * HID) / 4);
  gemm8p_kernel<0><<<dim3(NQKV / 256, NT / 256), 512, 0, stream>>>(
      hsb, wqb, b_qkv, Qb, Kb, Vb, nullptr, NT, NQKV, HID);
  cvt_kernel<<<2048, 256, 0, stream>>>(w_dense, wdb, (HID * HID) / 4);
  rope_kernel<<<(NB * NH * SEQ * 16) / 256, 256, 0, stream>>>(Qb, Kb, cosb, sinb);
  attn_kernel<<<dim3(SEQ / 128, NB * NH), 512, 0, stream>>>(Qb, Kb, Vb, aob);
  gemm8p_kernel<1><<<dim3(HID / 256, NT / 256), 512, 0, stream>>>(
      aob, wdb, b_dense, nullptr, nullptr, nullptr, out, NT, HID, HID);
}